// Round 7
// baseline (115.724 us; speedup 1.0000x reference)
//
#include <hip/hip_runtime.h>
#include <hip/hip_bf16.h>
#include <stdint.h>

typedef __attribute__((ext_vector_type(8))) short short8;
typedef __attribute__((ext_vector_type(4))) float floatx4;
typedef __attribute__((ext_vector_type(4))) int intx4;

// ---------------------------------------------------------------------------
// Threefry-2x32 (20 rounds), bit-exact vs JAX (verified r2: absmax 0.0).
// ---------------------------------------------------------------------------
__device__ __forceinline__ void threefry2x32(uint32_t k0, uint32_t k1,
                                             uint32_t& x0, uint32_t& x1) {
  const uint32_t ks2 = k0 ^ k1 ^ 0x1BD11BDAu;
  uint32_t ks[3] = {k0, k1, ks2};
  const int rot[8] = {13, 15, 26, 6, 17, 29, 16, 24};
  x0 += ks[0];
  x1 += ks[1];
#pragma unroll
  for (int i = 0; i < 5; ++i) {
#pragma unroll
    for (int j = 0; j < 4; ++j) {
      const int r = rot[(i & 1) * 4 + j];
      x0 += x1;
      x1 = (x1 << r) | (x1 >> (32 - r));
      x1 ^= x0;
    }
    x0 += ks[(i + 1) % 3];
    x1 += ks[(i + 2) % 3] + (uint32_t)(i + 1);
  }
}

__device__ __forceinline__ float dropmask(int core, int e, float v) {
  uint32_t f0 = 0u, f1 = (uint32_t)core;
  threefry2x32(0u, 42u, f0, f1);
  uint32_t a = 0u, b = (uint32_t)e;
  threefry2x32(f0, f1, a, b);
  uint32_t bits = a ^ b;
  float u = __uint_as_float((bits >> 9) | 0x3F800000u) - 1.0f;
  float m = (u < 0.8f) ? 1.0f : 0.0f;
  return v * m / 0.8f;
}

__device__ __forceinline__ unsigned short f2bf(float f) {  // RNE
  uint32_t u = __float_as_uint(f);
  uint32_t r = u + 0x7fffu + ((u >> 16) & 1u);
  return (unsigned short)(r >> 16);
}

union B2I { __hip_bfloat162 b; int i; };
__device__ __forceinline__ int pk_bf16(float lo, float hi) {
  B2I u;
  u.b = __float22bfloat162_rn(make_float2(lo, hi));
  return u.i;
}
union Frag { intx4 i; short8 s; };

// ---------------------------------------------------------------------------
// Prep: masked bf16 B matrices, pre-swizzled into MFMA B-fragment order
// (verified r3-r6). stage1: k = c*32+q*8+j (c<16). stage2: t=45q+c, m=t/5,
// nk=8*(t%5)+j (c<45, K'=1440, zeros for nk>=36 or invalid col).
// Also zero-inits out (linear_kernel accumulates with atomics).
// ---------------------------------------------------------------------------
__global__ void prep_kernel(const float* __restrict__ eps0,
                            const float* __restrict__ eps1,
                            unsigned short* __restrict__ bsw1,
                            unsigned short* __restrict__ bsw2,
                            float* __restrict__ out) {
  int idx = blockIdx.x * 256 + threadIdx.x;  // grid exactly 31232
  if (idx < 1280) out[idx] = 0.0f;
  if (idx < 8192) {
    int j = idx & 7, L = (idx >> 3) & 63, c = idx >> 9;
    int o = L & 15, q = L >> 4;
    int k = c * 32 + q * 8 + j;
    float v = 0.0f;
    if (o < 6) {
      int e = o * 512 + k;
      v = dropmask(0, e, eps0[e]);
    }
    bsw1[idx] = f2bf(v);
  } else {
    int t2 = idx - 8192;  // < 23040 = 45*512
    int j = t2 & 7, L = (t2 >> 3) & 63, c = t2 >> 9;
    int o = L & 15, q = L >> 4;
    int t = 45 * q + c;
    int m = t / 5, nk = 8 * (t % 5) + j;
    float v = 0.0f;
    if (o < 10 && nk < 36) {
      int e = o * 1296 + m * 36 + nk;
      v = dropmask(1, e, eps1[e]);
    }
    bsw2[t2] = f2bf(v);
  }
}

// 6-way select, cndmask chain (runtime k, constant element indices)
__device__ __forceinline__ float sel6(const float a[6], int k) {
  float r = a[0];
  r = (k == 1) ? a[1] : r;
  r = (k == 2) ? a[2] : r;
  r = (k == 3) ? a[3] : r;
  r = (k == 4) ? a[4] : r;
  r = (k == 5) ? a[5] : r;
  return r;
}

// ---------------------------------------------------------------------------
// Stage 1 via MFMA. B fragments (16 x 16B/lane = 64 VGPRs) loaded ONCE into
// registers from the pre-swizzled global array -> the K-loop is pure
// VALU+MFMA with zero memory ops (kills the r3-r6 per-iteration load->use
// latency chain). No LDS, no syncthreads.
// ---------------------------------------------------------------------------
__global__ __launch_bounds__(256, 2) void stage1_mfma(
    const float* __restrict__ x, const unsigned short* __restrict__ bsw1,
    float* __restrict__ h) {
  const int lane = threadIdx.x & 63;
  const int wave = (blockIdx.x * 256 + threadIdx.x) >> 6;  // 0..5407
  const int col = lane & 15, q = lane >> 4;

  // All 16 B fragments -> registers (coalesced dwordx4, lane stride 16B)
  intx4 bfr[16];
  const intx4* bsrc = (const intx4*)bsw1;
#pragma unroll
  for (int c = 0; c < 16; ++c) bfr[c] = bsrc[c * 64 + lane];

  const int pid = wave * 16 + col;
  const int b = pid / 676;
  const int rem = pid - b * 676;
  const int ii = rem / 26;
  const int jj = rem - ii * 26;

  const float2* x2 = (const float2*)x;
  float xv[9][2];
#pragma unroll
  for (int di = 0; di < 3; ++di)
#pragma unroll
    for (int dj = 0; dj < 3; ++dj) {
      float2 v = x2[(b * 28 + ii + di) * 28 + (jj + dj)];
      xv[di * 3 + dj][0] = v.x;
      xv[di * 3 + dj][1] = v.y;
    }

  float w3[8];
#pragma unroll
  for (int j = 0; j < 8; ++j)
    w3[j] = xv[6][(j >> 2) & 1] * xv[7][(j >> 1) & 1] * xv[8][j & 1];

  // chunk c -> u = 4c+q: c bits -> pixels 0..3, q bits -> pixels 4,5
  const float wq = xv[4][(q >> 1) & 1] * xv[5][q & 1];
  float t01[4], t23[4];
#pragma unroll
  for (int a = 0; a < 2; ++a)
#pragma unroll
    for (int d = 0; d < 2; ++d) {
      t01[a * 2 + d] = xv[0][a] * xv[1][d];
      t23[a * 2 + d] = xv[2][a] * xv[3][d] * wq;
    }

  floatx4 acc0 = {0.f, 0.f, 0.f, 0.f};
  floatx4 acc1 = {0.f, 0.f, 0.f, 0.f};
#pragma unroll
  for (int c = 0; c < 16; ++c) {
    Frag bf;
    bf.i = bfr[c];
    const float w = t01[c >> 2] * t23[c & 3];  // compile-time indices
    Frag af;
    af.i.x = pk_bf16(w * w3[0], w * w3[1]);
    af.i.y = pk_bf16(w * w3[2], w * w3[3]);
    af.i.z = pk_bf16(w * w3[4], w * w3[5]);
    af.i.w = pk_bf16(w * w3[6], w * w3[7]);
    if (c & 1)
      acc1 = __builtin_amdgcn_mfma_f32_16x16x32_bf16(af.s, bf.s, acc1, 0, 0, 0);
    else
      acc0 = __builtin_amdgcn_mfma_f32_16x16x32_bf16(af.s, bf.s, acc0, 0, 0, 0);
  }
  const floatx4 acc = acc0 + acc1;
  if (col < 6) {
#pragma unroll
    for (int r = 0; r < 4; ++r) h[(wave * 16 + q * 4 + r) * 6 + col] = acc[r];
  }
}

// ---------------------------------------------------------------------------
// Stage 2 via MFMA. B fragments register-resident in two phases (25+20
// chunks reusing a 25-entry array = 100 VGPRs; live ~170 < 256 cap). One
// vmcnt wait per phase instead of one per chunk. K-loop body is pure
// VALU+MFMA. No LDS.
// ---------------------------------------------------------------------------
__global__ __launch_bounds__(256, 2) void stage2_mfma(
    const float* __restrict__ h, const unsigned short* __restrict__ bsw2,
    float* __restrict__ flat) {
  const int lane = threadIdx.x & 63;
  const int wave = (blockIdx.x * 256 + threadIdx.x) >> 6;  // 0..4999
  const int col = lane & 15, q = lane >> 4;
  const int pid = wave * 16 + col;
  const int b = pid / 625;
  const int rem = pid - b * 625;
  const int ii = rem / 25;
  const int jj = rem - ii * 25;

  const intx4* bsrc = (const intx4*)bsw2;
  intx4 bfr[25];
#pragma unroll
  for (int c = 0; c < 25; ++c) bfr[c] = bsrc[c * 64 + lane];

  const float* hp = h + ((b * 26 + ii) * 26 + jj) * 6;
  float h00[6], h01[6], h10[6], h11[6];
  const float2* hp2a = (const float2*)(hp);
  const float2* hp2b = (const float2*)(hp + 156);
#pragma unroll
  for (int t = 0; t < 3; ++t) {
    float2 v0 = hp2a[t], v1 = hp2a[t + 3], v2 = hp2b[t], v3 = hp2b[t + 3];
    h00[2 * t] = v0.x; h00[2 * t + 1] = v0.y;
    h01[2 * t] = v1.x; h01[2 * t + 1] = v1.y;
    h10[2 * t] = v2.x; h10[2 * t + 1] = v2.y;
    h11[2 * t] = v3.x; h11[2 * t + 1] = v3.y;
  }

  floatx4 acc0 = {0.f, 0.f, 0.f, 0.f};
  floatx4 acc1 = {0.f, 0.f, 0.f, 0.f};

  // Phase 1: chunks 0..24 (d = 0..4)
#pragma unroll
  for (int d = 0; d < 5; ++d) {
    const int m = 9 * q + d;
    const int ia = (m * 43) >> 8;  // m/6 exact for m < 54
    const int ic = m - ia * 6;
    const float p01 = sel6(h00, ia) * sel6(h01, ic);
    float ph[6];
#pragma unroll
    for (int a = 0; a < 6; ++a) ph[a] = p01 * h10[a];
#pragma unroll
    for (int e = 0; e < 5; ++e) {
      Frag bf;
      bf.i = bfr[d * 5 + e];
      const int n0 = 8 * e;
      float av[8];
#pragma unroll
      for (int j = 0; j < 8; ++j) {
        const int n = n0 + j;  // compile-time after unroll
        av[j] = (n < 36) ? ph[n / 6] * h11[n % 6] : 0.0f;
      }
      Frag af;
      af.i.x = pk_bf16(av[0], av[1]);
      af.i.y = pk_bf16(av[2], av[3]);
      af.i.z = pk_bf16(av[4], av[5]);
      af.i.w = pk_bf16(av[6], av[7]);
      if (e & 1)
        acc1 = __builtin_amdgcn_mfma_f32_16x16x32_bf16(af.s, bf.s, acc1, 0, 0, 0);
      else
        acc0 = __builtin_amdgcn_mfma_f32_16x16x32_bf16(af.s, bf.s, acc0, 0, 0, 0);
    }
  }

  // Phase 2: reload chunks 25..44 into bfr[0..19], consume (d = 5..8)
#pragma unroll
  for (int c = 0; c < 20; ++c) bfr[c] = bsrc[(25 + c) * 64 + lane];
#pragma unroll
  for (int d = 5; d < 9; ++d) {
    const int m = 9 * q + d;
    const int ia = (m * 43) >> 8;
    const int ic = m - ia * 6;
    const float p01 = sel6(h00, ia) * sel6(h01, ic);
    float ph[6];
#pragma unroll
    for (int a = 0; a < 6; ++a) ph[a] = p01 * h10[a];
#pragma unroll
    for (int e = 0; e < 5; ++e) {
      Frag bf;
      bf.i = bfr[(d - 5) * 5 + e];
      const int n0 = 8 * e;
      float av[8];
#pragma unroll
      for (int j = 0; j < 8; ++j) {
        const int n = n0 + j;
        av[j] = (n < 36) ? ph[n / 6] * h11[n % 6] : 0.0f;
      }
      Frag af;
      af.i.x = pk_bf16(av[0], av[1]);
      af.i.y = pk_bf16(av[2], av[3]);
      af.i.z = pk_bf16(av[4], av[5]);
      af.i.w = pk_bf16(av[6], av[7]);
      if (e & 1)
        acc1 = __builtin_amdgcn_mfma_f32_16x16x32_bf16(af.s, bf.s, acc1, 0, 0, 0);
      else
        acc0 = __builtin_amdgcn_mfma_f32_16x16x32_bf16(af.s, bf.s, acc0, 0, 0, 0);
    }
  }

  const floatx4 acc = acc0 + acc1;
  if (col < 10) {
#pragma unroll
    for (int r = 0; r < 4; ++r)
      flat[(wave * 16 + q * 4 + r) * 10 + col] = acc[r];
  }
}

// ---------------------------------------------------------------------------
// Linear, split over f: grid (128, 5). Block-reduce + one atomicAdd per o.
// out zero-initialized by prep_kernel.
// ---------------------------------------------------------------------------
__global__ __launch_bounds__(256) void linear_kernel(
    const float* __restrict__ flat, const float* __restrict__ W,
    const float* __restrict__ bias, float* __restrict__ out) {
  const int b = blockIdx.x;
  const int c = blockIdx.y;  // 0..4
  const float* fb = flat + b * 6250 + c * 1250;
  const float* Wc = W + c * 1250;
  float acc[10];
#pragma unroll
  for (int o = 0; o < 10; ++o) acc[o] = 0.0f;
  for (int f = threadIdx.x; f < 1250; f += 256) {
    const float v = fb[f];
#pragma unroll
    for (int o = 0; o < 10; ++o) acc[o] += v * Wc[o * 6250 + f];
  }
#pragma unroll
  for (int o = 0; o < 10; ++o) {
#pragma unroll
    for (int s = 32; s > 0; s >>= 1) acc[o] += __shfl_xor(acc[o], s, 64);
  }
  __shared__ float red[4][10];
  const int lane = threadIdx.x & 63, wv = threadIdx.x >> 6;
  if (lane == 0) {
#pragma unroll
    for (int o = 0; o < 10; ++o) red[wv][o] = acc[o];
  }
  __syncthreads();
  if (threadIdx.x < 10) {
    const int o = threadIdx.x;
    float r = red[0][o] + red[1][o] + red[2][o] + red[3][o];
    if (c == 0) r += bias[o];
    atomicAdd(&out[b * 10 + o], r);
  }
}

// ---------------------------------------------------------------------------
extern "C" void kernel_launch(void* const* d_in, const int* in_sizes, int n_in,
                              void* d_out, int out_size, void* d_ws,
                              size_t ws_size, hipStream_t stream) {
  const float* x = (const float*)d_in[0];     // (128,28,28,2)
  const float* eps0 = (const float*)d_in[1];  // (6,512)
  const float* eps1 = (const float*)d_in[2];  // (10,1296)
  const float* W = (const float*)d_in[3];     // (10,6250)
  const float* bias = (const float*)d_in[4];  // (10,)
  float* out = (float*)d_out;                 // (128,10)

  char* wsb = (char*)d_ws;
  unsigned short* bsw1 = (unsigned short*)wsb;            // 16384 B
  unsigned short* bsw2 = (unsigned short*)(wsb + 16384);  // 46080 B
  float* h = (float*)(wsb + 65536);               // 519168 floats
  float* flat = (float*)(wsb + 65536 + 2076672);  // 800000 floats

  hipLaunchKernelGGL(prep_kernel, dim3(122), dim3(256), 0, stream, eps0, eps1,
                     bsw1, bsw2, out);
  hipLaunchKernelGGL(stage1_mfma, dim3(1352), dim3(256), 0, stream, x, bsw1,
                     h);
  hipLaunchKernelGGL(stage2_mfma, dim3(1250), dim3(256), 0, stream, h, bsw2,
                     flat);
  hipLaunchKernelGGL(linear_kernel, dim3(128, 5), dim3(256), 0, stream, flat,
                     W, bias, out);
}

// Round 8
// 103.805 us; speedup vs baseline: 1.1148x; 1.1148x over previous
//
#include <hip/hip_runtime.h>
#include <hip/hip_bf16.h>
#include <stdint.h>

typedef __attribute__((ext_vector_type(8))) short short8;
typedef __attribute__((ext_vector_type(4))) float floatx4;
typedef __attribute__((ext_vector_type(4))) int intx4;

// ---------------------------------------------------------------------------
// Threefry-2x32 (20 rounds), bit-exact vs JAX (verified r2: absmax 0.0).
// ---------------------------------------------------------------------------
__device__ __forceinline__ void threefry2x32(uint32_t k0, uint32_t k1,
                                             uint32_t& x0, uint32_t& x1) {
  const uint32_t ks2 = k0 ^ k1 ^ 0x1BD11BDAu;
  uint32_t ks[3] = {k0, k1, ks2};
  const int rot[8] = {13, 15, 26, 6, 17, 29, 16, 24};
  x0 += ks[0];
  x1 += ks[1];
#pragma unroll
  for (int i = 0; i < 5; ++i) {
#pragma unroll
    for (int j = 0; j < 4; ++j) {
      const int r = rot[(i & 1) * 4 + j];
      x0 += x1;
      x1 = (x1 << r) | (x1 >> (32 - r));
      x1 ^= x0;
    }
    x0 += ks[(i + 1) % 3];
    x1 += ks[(i + 2) % 3] + (uint32_t)(i + 1);
  }
}

__device__ __forceinline__ float dropmask(int core, int e, float v) {
  uint32_t f0 = 0u, f1 = (uint32_t)core;
  threefry2x32(0u, 42u, f0, f1);
  uint32_t a = 0u, b = (uint32_t)e;
  threefry2x32(f0, f1, a, b);
  uint32_t bits = a ^ b;
  float u = __uint_as_float((bits >> 9) | 0x3F800000u) - 1.0f;
  float m = (u < 0.8f) ? 1.0f : 0.0f;
  return v * m / 0.8f;
}

__device__ __forceinline__ unsigned short f2bf(float f) {  // RNE
  uint32_t u = __float_as_uint(f);
  uint32_t r = u + 0x7fffu + ((u >> 16) & 1u);
  return (unsigned short)(r >> 16);
}

union B2I { __hip_bfloat162 b; int i; };
__device__ __forceinline__ int pk_bf16(float lo, float hi) {
  B2I u;
  u.b = __float22bfloat162_rn(make_float2(lo, hi));
  return u.i;
}
union Frag { intx4 i; short8 s; };

// ---------------------------------------------------------------------------
// Prep: masked bf16 B matrices, pre-swizzled into MFMA B-fragment order
// (verified r3-r7). stage1: k = c*32+q*8+j (c<16). stage2: t=45q+c, m=t/5,
// nk=8*(t%5)+j (c<45, K'=1440, zeros for nk>=36 or invalid col).
// ---------------------------------------------------------------------------
__global__ void prep_kernel(const float* __restrict__ eps0,
                            const float* __restrict__ eps1,
                            unsigned short* __restrict__ bsw1,
                            unsigned short* __restrict__ bsw2) {
  int idx = blockIdx.x * 256 + threadIdx.x;  // grid exactly 31232
  if (idx < 8192) {
    int j = idx & 7, L = (idx >> 3) & 63, c = idx >> 9;
    int o = L & 15, q = L >> 4;
    int k = c * 32 + q * 8 + j;
    float v = 0.0f;
    if (o < 6) {
      int e = o * 512 + k;
      v = dropmask(0, e, eps0[e]);
    }
    bsw1[idx] = f2bf(v);
  } else {
    int t2 = idx - 8192;  // < 23040 = 45*512
    int j = t2 & 7, L = (t2 >> 3) & 63, c = t2 >> 9;
    int o = L & 15, q = L >> 4;
    int t = 45 * q + c;
    int m = t / 5, nk = 8 * (t % 5) + j;
    float v = 0.0f;
    if (o < 10 && nk < 36) {
      int e = o * 1296 + m * 36 + nk;
      v = dropmask(1, e, eps1[e]);
    }
    bsw2[t2] = f2bf(v);
  }
}

// 6-way select, cndmask chain (runtime k, constant element indices)
__device__ __forceinline__ float sel6(const float a[6], int k) {
  float r = a[0];
  r = (k == 1) ? a[1] : r;
  r = (k == 2) ? a[2] : r;
  r = (k == 3) ? a[3] : r;
  r = (k == 4) ? a[4] : r;
  r = (k == 5) ? a[5] : r;
  return r;
}

// ---------------------------------------------------------------------------
// Fused kernel: one block (512 thr, 8 waves) per batch image. h and flat in
// LDS (no global round-trip). B1 then B2 register-resident (loaded once per
// wave). Linear fused at the end: direct store, no atomics.
// ---------------------------------------------------------------------------
__global__ __launch_bounds__(512, 2) void fused_kernel(
    const float* __restrict__ x, const unsigned short* __restrict__ bsw1,
    const unsigned short* __restrict__ bsw2, const float* __restrict__ W,
    const float* __restrict__ bias, float* __restrict__ out) {
  __shared__ float h_lds[4056];     // 26*26*6
  __shared__ float flat_lds[6250];  // 25*25*10
  __shared__ float red[8][10];

  const int b = blockIdx.x;
  const int tid = threadIdx.x;
  const int lane = tid & 63;
  const int wv = tid >> 6;  // 0..7
  const int col = lane & 15, q = lane >> 4;

  // ---- B1 fragments -> registers (64 VGPR) ----
  intx4 bfr1[16];
  const intx4* bsrc1 = (const intx4*)bsw1;
#pragma unroll
  for (int c = 0; c < 16; ++c) bfr1[c] = bsrc1[c * 64 + lane];

  // ---- Stage 1: 43 tiles of 16 pixels over 676, wave-strided ----
  const float2* x2 = (const float2*)x + b * 784;  // 28*28 float2 per image
#pragma unroll 1
  for (int tile = wv; tile < 43; tile += 8) {
    const int p_raw = tile * 16 + col;
    const int p = p_raw < 676 ? p_raw : 675;  // clamp for addressing
    const int ii = p / 26, jj = p - (p / 26) * 26;

    float xv[9][2];
#pragma unroll
    for (int di = 0; di < 3; ++di)
#pragma unroll
      for (int dj = 0; dj < 3; ++dj) {
        float2 v = x2[(ii + di) * 28 + (jj + dj)];
        xv[di * 3 + dj][0] = v.x;
        xv[di * 3 + dj][1] = v.y;
      }

    float w3[8];
#pragma unroll
    for (int j = 0; j < 8; ++j)
      w3[j] = xv[6][(j >> 2) & 1] * xv[7][(j >> 1) & 1] * xv[8][j & 1];

    const float wq = xv[4][(q >> 1) & 1] * xv[5][q & 1];
    float t01[4], t23[4];
#pragma unroll
    for (int a = 0; a < 2; ++a)
#pragma unroll
      for (int d = 0; d < 2; ++d) {
        t01[a * 2 + d] = xv[0][a] * xv[1][d];
        t23[a * 2 + d] = xv[2][a] * xv[3][d] * wq;
      }

    floatx4 acc0 = {0.f, 0.f, 0.f, 0.f};
    floatx4 acc1 = {0.f, 0.f, 0.f, 0.f};
#pragma unroll
    for (int c = 0; c < 16; ++c) {
      Frag bf;
      bf.i = bfr1[c];
      const float w = t01[c >> 2] * t23[c & 3];
      Frag af;
      af.i.x = pk_bf16(w * w3[0], w * w3[1]);
      af.i.y = pk_bf16(w * w3[2], w * w3[3]);
      af.i.z = pk_bf16(w * w3[4], w * w3[5]);
      af.i.w = pk_bf16(w * w3[6], w * w3[7]);
      if (c & 1)
        acc1 = __builtin_amdgcn_mfma_f32_16x16x32_bf16(af.s, bf.s, acc1, 0, 0, 0);
      else
        acc0 = __builtin_amdgcn_mfma_f32_16x16x32_bf16(af.s, bf.s, acc0, 0, 0, 0);
    }
    const floatx4 acc = acc0 + acc1;
    if (col < 6) {
#pragma unroll
      for (int r = 0; r < 4; ++r) {
        const int pp = tile * 16 + q * 4 + r;
        if (pp < 676) h_lds[pp * 6 + col] = acc[r];
      }
    }
  }

  // ---- B2 fragments -> registers (180 VGPR; bfr1 dead, regs reused) ----
  intx4 bfr2[45];
  const intx4* bsrc2 = (const intx4*)bsw2;
#pragma unroll
  for (int c = 0; c < 45; ++c) bfr2[c] = bsrc2[c * 64 + lane];

  __syncthreads();  // h_lds complete

  // ---- Stage 2: 40 tiles of 16 pixels over 625, wave-strided ----
#pragma unroll 1
  for (int tile = wv; tile < 40; tile += 8) {
    const int p_raw = tile * 16 + col;
    const int p = p_raw < 625 ? p_raw : 624;  // clamp for addressing
    const int ii = p / 25, jj = p - (p / 25) * 25;
    const int hbase = (ii * 26 + jj) * 6;

    float h00[6], h01[6], h10[6], h11[6];
#pragma unroll
    for (int t = 0; t < 6; ++t) {
      h00[t] = h_lds[hbase + t];
      h01[t] = h_lds[hbase + 6 + t];
      h10[t] = h_lds[hbase + 156 + t];
      h11[t] = h_lds[hbase + 162 + t];
    }

    floatx4 acc0 = {0.f, 0.f, 0.f, 0.f};
    floatx4 acc1 = {0.f, 0.f, 0.f, 0.f};
#pragma unroll
    for (int d = 0; d < 9; ++d) {  // chunk c = 5d + e; m = 9q + d
      const int m = 9 * q + d;
      const int ia = (m * 43) >> 8;  // m/6 exact for m < 54
      const int ic = m - ia * 6;
      const float p01 = sel6(h00, ia) * sel6(h01, ic);
      float ph[6];
#pragma unroll
      for (int a = 0; a < 6; ++a) ph[a] = p01 * h10[a];
#pragma unroll
      for (int e = 0; e < 5; ++e) {
        Frag bf;
        bf.i = bfr2[d * 5 + e];
        const int n0 = 8 * e;
        float av[8];
#pragma unroll
        for (int j = 0; j < 8; ++j) {
          const int n = n0 + j;  // compile-time after unroll
          av[j] = (n < 36) ? ph[n / 6] * h11[n % 6] : 0.0f;
        }
        Frag af;
        af.i.x = pk_bf16(av[0], av[1]);
        af.i.y = pk_bf16(av[2], av[3]);
        af.i.z = pk_bf16(av[4], av[5]);
        af.i.w = pk_bf16(av[6], av[7]);
        if (e & 1)
          acc1 = __builtin_amdgcn_mfma_f32_16x16x32_bf16(af.s, bf.s, acc1, 0, 0, 0);
        else
          acc0 = __builtin_amdgcn_mfma_f32_16x16x32_bf16(af.s, bf.s, acc0, 0, 0, 0);
      }
    }
    const floatx4 acc = acc0 + acc1;
    if (col < 10) {
#pragma unroll
      for (int r = 0; r < 4; ++r) {
        const int pp = tile * 16 + q * 4 + r;
        if (pp < 625) flat_lds[pp * 10 + col] = acc[r];
      }
    }
  }
  __syncthreads();  // flat_lds complete

  // ---- Linear: out[b,o] = bias[o] + sum_f flat[f] * W[o,f] ----
  float acc[10];
#pragma unroll
  for (int o = 0; o < 10; ++o) acc[o] = 0.0f;
  for (int f = tid; f < 6250; f += 512) {
    const float v = flat_lds[f];
#pragma unroll
    for (int o = 0; o < 10; ++o) acc[o] += v * W[o * 6250 + f];
  }
#pragma unroll
  for (int o = 0; o < 10; ++o) {
#pragma unroll
    for (int s = 32; s > 0; s >>= 1) acc[o] += __shfl_xor(acc[o], s, 64);
  }
  if (lane == 0) {
#pragma unroll
    for (int o = 0; o < 10; ++o) red[wv][o] = acc[o];
  }
  __syncthreads();
  if (tid < 10) {
    float r = bias[tid];
#pragma unroll
    for (int ww = 0; ww < 8; ++ww) r += red[ww][tid];
    out[b * 10 + tid] = r;
  }
}

// ---------------------------------------------------------------------------
extern "C" void kernel_launch(void* const* d_in, const int* in_sizes, int n_in,
                              void* d_out, int out_size, void* d_ws,
                              size_t ws_size, hipStream_t stream) {
  const float* x = (const float*)d_in[0];     // (128,28,28,2)
  const float* eps0 = (const float*)d_in[1];  // (6,512)
  const float* eps1 = (const float*)d_in[2];  // (10,1296)
  const float* W = (const float*)d_in[3];     // (10,6250)
  const float* bias = (const float*)d_in[4];  // (10,)
  float* out = (float*)d_out;                 // (128,10)

  char* wsb = (char*)d_ws;
  unsigned short* bsw1 = (unsigned short*)wsb;            // 16384 B
  unsigned short* bsw2 = (unsigned short*)(wsb + 16384);  // 46080 B

  hipLaunchKernelGGL(prep_kernel, dim3(122), dim3(256), 0, stream, eps0, eps1,
                     bsw1, bsw2);
  hipLaunchKernelGGL(fused_kernel, dim3(128), dim3(512), 0, stream, x, bsw1,
                     bsw2, W, bias, out);
}